// Round 7
// baseline (423.654 us; speedup 1.0000x reference)
//
#include <hip/hip_runtime.h>
#include <stdint.h>

#define SEQ   2048
#define HID   4096
#define NQH   32
#define NKVH  8
#define HD    128
#define QKVN  6144   // (32 + 2*8) * 128

typedef uint16_t u16;
typedef __attribute__((ext_vector_type(8))) short bf16x8;
typedef __attribute__((ext_vector_type(4))) float f32x4;
typedef __attribute__((ext_vector_type(4))) unsigned int u32x4;

static __device__ __forceinline__ float bf2f(u16 h){
  union { float f; unsigned int u; } v; v.u = ((unsigned int)h) << 16; return v.f;
}
static __device__ __forceinline__ u16 f2bf(float f){
  unsigned int u = __float_as_uint(f);
  return (u16)((u + 0x7fffu + ((u >> 16) & 1u)) >> 16);  // RNE, finite inputs only
}
static __device__ __forceinline__ f32x4 mfma16(bf16x8 a, bf16x8 b, f32x4 c){
  return __builtin_amdgcn_mfma_f32_16x16x32_bf16(a, b, c, 0, 0, 0);
}
static __device__ __forceinline__ void gload16(const void* g, void* l){
  __builtin_amdgcn_global_load_lds((const __attribute__((address_space(1))) void*)g,
                                   (__attribute__((address_space(3))) void*)l, 16, 0, 0);
}

// ---------------- fp32 -> bf16 elementwise (n4 = n/4) ----------------
__global__ void k_cvt(const float* __restrict__ src, u16* __restrict__ dst, int n4){
  int i = blockIdx.x * blockDim.x + threadIdx.x;
  if (i >= n4) return;
  float4 v = ((const float4*)src)[i];
  uint2 o;
  o.x = (unsigned)f2bf(v.x) | ((unsigned)f2bf(v.y) << 16);
  o.y = (unsigned)f2bf(v.z) | ((unsigned)f2bf(v.w) << 16);
  ((uint2*)dst)[i] = o;
}

// ---------------- src[K][N] fp32 -> dst[N][K] bf16 (transpose-convert) ----------------
__global__ void k_transpose_cvt(const float* __restrict__ src, u16* __restrict__ dst, int K, int N){
  __shared__ float t[32][33];
  int n0 = blockIdx.x * 32, k0 = blockIdx.y * 32;
  int tx = threadIdx.x, ty = threadIdx.y;
#pragma unroll
  for (int i = 0; i < 32; i += 8)
    t[ty + i][tx] = src[(size_t)(k0 + ty + i) * N + n0 + tx];
  __syncthreads();
#pragma unroll
  for (int i = 0; i < 32; i += 8)
    dst[(size_t)(n0 + ty + i) * K + k0 + tx] = f2bf(t[tx][ty + i]);
}

// ---------------- C[M][N] = A[M][K] @ Bt[N][K]^T, bf16 in, OUTBF? bf16 : fp32 out ----------------
// K-HALF RING-4 pipeline: tile BMx256, slot = one K-half (A[BM][32] + B[256][32]).
// Per body h: barrier -> stage slot h+3 + COUNTED vmcnt (confirms h+2, ~2 bodies slack)
// -> ds_read frags(h+1) + COUNTED lgkmcnt (drains frags(h), which drained under the
// previous body's MFMA) -> sched_barrier (rule 18) -> setprio(1) MI*4 MFMA setprio(0).
// No drain-to-0 in steady state (T4). One barrier per body. Double register sets,
// statically named (rule 20). Cross-wave visibility: gload confirmed by issuing wave's
// vmcnt at body h-1, all waves pass body-h barrier before any read of that slot.
// 16B-granule XOR swizzle key=(row>>1)&3 both sides (r4-r6: 0 bank conflicts).
template<int MI, int OUTBF>
__global__ __launch_bounds__(512) void k_gemm(const u16* __restrict__ A, const u16* __restrict__ Bt,
                                              void* __restrict__ Cv, int M, int N, int K){
  constexpr int BM  = MI * 32;          // 256 (MI=8) or 128 (MI=4)
  constexpr int LPB = (MI == 8) ? 4 : 3; // gloads per body
  constexpr int RPB = MI + 4;            // ds_reads per body
  __shared__ __align__(16) u16 Asm[4][BM][32];
  __shared__ __align__(16) u16 Bsm[4][256][32];
  const int tid = threadIdx.x, lane = tid & 63, wid = tid >> 6;
  const int wm = wid >> 2, wn = wid & 3;          // 2M x 4N waves
  const int l16 = lane & 15, lhi = lane >> 4;
  const int swz = (l16 >> 1) & 3;                  // read-side swizzle key = (row>>1)&3
  const size_t brow = (size_t)blockIdx.y * BM, bcol = (size_t)blockIdx.x * 256;

  const f32x4 vz = {0.f, 0.f, 0.f, 0.f};
  f32x4 acc[MI][4];
#pragma unroll
  for (int m = 0; m < MI; m++)
#pragma unroll
    for (int n = 0; n < 4; n++) acc[m][n] = vz;

  // staging: round = 64 lanes x 16B = 16 rows x 32cols. lane -> row rsub=l>>2, granule l&3.
  // source granule pre-swizzled with key (row>>1)&3 = ((l>>3)&3)  (row-base mod 32 == 0).
  const int rsub = lane >> 2;
  const int gsrc = ((lane & 3) ^ ((lane >> 3) & 3)) * 8;
  const u16* Ag = A  + (brow + (MI == 8 ? wid * 32 : wid * 16) + rsub) * (size_t)K + gsrc;
  const u16* Bg = Bt + (bcol + wid * 32 + rsub) * (size_t)K + gsrc;
  const int NH = K >> 5;                 // K-halves

#define STAGE(H) do{                                                            \
    const int sl_ = (H) & 3; const size_t ko_ = (size_t)(H) * 32;               \
    if (MI == 8){                                                               \
      gload16(Ag + ko_,                  &Asm[sl_][wid*32][0]);                 \
      gload16(Ag + (size_t)16*K + ko_,   &Asm[sl_][wid*32 + 16][0]);            \
    } else {                                                                    \
      gload16(Ag + ko_,                  &Asm[sl_][wid*16][0]);                 \
    }                                                                           \
    gload16(Bg + ko_,                    &Bsm[sl_][wid*32][0]);                 \
    gload16(Bg + (size_t)16*K + ko_,     &Bsm[sl_][wid*32 + 16][0]);            \
  }while(0)

#define RDFRAGS(H, aS, bS) do{                                                  \
    const int sl_ = (H) & 3;                                                    \
    _Pragma("unroll")                                                           \
    for (int mi = 0; mi < MI; mi++)                                             \
      aS[mi] = *(const bf16x8*)&Asm[sl_][wm*(BM/2) + mi*16 + l16][(lhi ^ swz) << 3]; \
    _Pragma("unroll")                                                           \
    for (int ni = 0; ni < 4; ni++)                                              \
      bS[ni] = *(const bf16x8*)&Bsm[sl_][wn*64 + ni*16 + l16][(lhi ^ swz) << 3]; \
  }while(0)

#define BODY(H, aC, bC, aN, bN) do{                                             \
    __builtin_amdgcn_s_barrier();                                               \
    if ((H) + 3 < NH){                                                          \
      STAGE((H) + 3);                                                           \
      asm volatile("s_waitcnt vmcnt(%0)" :: "i"(LPB) : "memory");               \
    } else {                                                                    \
      asm volatile("s_waitcnt vmcnt(0)" ::: "memory");                          \
    }                                                                           \
    if ((H) + 1 < NH){                                                          \
      RDFRAGS((H) + 1, aN, bN);                                                 \
      asm volatile("s_waitcnt lgkmcnt(%0)" :: "i"(RPB) : "memory");             \
    } else {                                                                    \
      asm volatile("s_waitcnt lgkmcnt(0)" ::: "memory");                        \
    }                                                                           \
    __builtin_amdgcn_sched_barrier(0);                                          \
    __builtin_amdgcn_s_setprio(1);                                              \
    _Pragma("unroll")                                                           \
    for (int mi = 0; mi < MI; mi++)                                             \
      _Pragma("unroll")                                                         \
      for (int ni = 0; ni < 4; ni++)                                            \
        acc[mi][ni] = mfma16(aC[mi], bC[ni], acc[mi][ni]);                      \
    __builtin_amdgcn_s_setprio(0);                                              \
  }while(0)

  // prologue: stage halves 0-2, full drain ONCE (cold start), frags(0)
  STAGE(0); STAGE(1); STAGE(2);
  asm volatile("s_waitcnt vmcnt(0)" ::: "memory");
  __builtin_amdgcn_s_barrier();
  bf16x8 aX[MI], bX[4], aY[MI], bY[4];
  RDFRAGS(0, aX, bX);

  for (int u = 0; u < (NH >> 1); ++u){
    BODY(2*u,     aX, bX, aY, bY);
    BODY(2*u + 1, aY, bY, aX, bX);
  }
#undef STAGE
#undef RDFRAGS
#undef BODY

  // epilogue: C/D layout col=l16, row=lhi*4+i
#pragma unroll
  for (int mi = 0; mi < MI; mi++)
#pragma unroll
    for (int ni = 0; ni < 4; ni++)
#pragma unroll
      for (int i = 0; i < 4; i++){
        size_t row = brow + wm*(BM/2) + mi*16 + lhi*4 + i;
        size_t col = bcol + wn*64 + ni*16 + l16;
        if (OUTBF) ((u16*)Cv)[row * (size_t)N + col] = f2bf(acc[mi][ni][i]);
        else       ((float*)Cv)[row * (size_t)N + col] = acc[mi][ni][i];
      }
}

// ---------------- RMSNorm + RoPE: qkv bf16 -> Q[h][t][d], K[h][t][d] (scale folded into Q) ----------------
__global__ __launch_bounds__(256) void k_rmsrope(const u16* __restrict__ qkv, const float* __restrict__ cosp,
                                                 const float* __restrict__ sinp, const float* __restrict__ qw,
                                                 const float* __restrict__ kw, u16* __restrict__ Qr,
                                                 u16* __restrict__ Kr){
  int t = blockIdx.x;
  int lane = threadIdx.x & 63, w = threadIdx.x >> 6;
  int hh = blockIdx.y * 4 + w;          // 0..39: 32 q heads + 8 k heads
  bool isq = hh < NQH;
  int hl = isq ? hh : hh - NQH;
  const u16* src = qkv + (size_t)t * QKVN + (isq ? hl * HD : NQH * HD + hl * HD);
  unsigned u = *(const unsigned*)(src + 2 * lane);       // d = 2*lane, 2*lane+1
  float x0 = bf2f((u16)(u & 0xffffu)), x1 = bf2f((u16)(u >> 16));
  float ss = x0 * x0 + x1 * x1;
#pragma unroll
  for (int m = 1; m < 64; m <<= 1) ss += __shfl_xor(ss, m);
  float rs = rsqrtf(ss * (1.f / HD) + 1e-6f);
  const float* wp = isq ? qw : kw;
  float w0 = wp[2 * lane], w1 = wp[2 * lane + 1];
  float xn0 = x0 * rs * w0, xn1 = x1 * rs * w1;
  float p0 = __shfl_xor(xn0, 32), p1 = __shfl_xor(xn1, 32);  // rotate-half partner
  int j0 = (2 * lane) & 63;
  float c0 = cosp[t * 64 + j0], c1 = cosp[t * 64 + j0 + 1];
  float s0 = sinp[t * 64 + j0], s1 = sinp[t * 64 + j0 + 1];
  float o0, o1;
  if (lane < 32){ o0 = xn0 * c0 - p0 * s0; o1 = xn1 * c1 - p1 * s1; }
  else          { o0 = xn0 * c0 + p0 * s0; o1 = xn1 * c1 + p1 * s1; }
  if (isq){ o0 *= 0.08838834764831845f; o1 *= 0.08838834764831845f; }  // D^-0.5
  u16* dst = isq ? (Qr + ((size_t)hl * SEQ + t) * HD) : (Kr + ((size_t)hl * SEQ + t) * HD);
  *(unsigned*)(dst + 2 * lane) = (unsigned)f2bf(o0) | ((unsigned)f2bf(o1) << 16);
}

// ---------------- V slice of qkv -> VT[h][d][t] bf16 ----------------
__global__ void k_vt(const u16* __restrict__ qkv, u16* __restrict__ VT){
  __shared__ u16 t[32][33];
  int t0 = blockIdx.x * 32, d0 = blockIdx.y * 32, hv = blockIdx.z;
  int tx = threadIdx.x, ty = threadIdx.y;
#pragma unroll
  for (int i = 0; i < 32; i += 8)
    t[ty + i][tx] = qkv[(size_t)(t0 + ty + i) * QKVN + (NQH + NKVH) * HD + hv * HD + d0 + tx];
  __syncthreads();
#pragma unroll
  for (int i = 0; i < 32; i += 8)
    VT[((size_t)hv * HD + d0 + ty + i) * SEQ + t0 + tx] = t[tx][ty + i];
}

// ---------------- causal GQA flash attention ----------------
// 512 blocks (8 waves, 512 thr): one 128-row q-tile per block, longest-first.
// bid -> kvg=bid&7 (XCD L2 locality), J=15-(rr>>2) desc.
// K[64][128] and VT[128][64] double-buffered in LDS via global_load_lds with
// G21 XOR-swizzle (linear dest + inverse-swizzled source + swizzled ds_read).
// One barrier per KV tile; tile t+1 prefetch issued at trip t start.
__global__ __launch_bounds__(512, 2) void k_attn(const u16* __restrict__ Q, const u16* __restrict__ Kg,
                                                 const u16* __restrict__ VTg, u16* __restrict__ AO){
  __shared__ __align__(16) u16 Ksm[2][64][128];   // [buf][kv][d], 16B-granule swizzled
  __shared__ __align__(16) u16 Vsm[2][128][64];   // [buf][d][kv], swizzled
  __shared__ __align__(16) u16 Psm[8][16][72];    // per-wave P [q][kv]
  int tid = threadIdx.x, lane = tid & 63, wid = tid >> 6;
  int l16 = lane & 15, lhi = lane >> 4;
  int bid = blockIdx.x;
  int kvg = bid & 7, rr = bid >> 3;               // 64 blocks per kv-group
  int J = 15 - (rr >> 2);                         // longest-first
  int hq = kvg * 4 + (rr & 3);
  int qb = J * 128;
  const u16* Kh = Kg  + (size_t)kvg * SEQ * HD;
  const u16* Vh = VTg + (size_t)kvg * HD * SEQ;
  const u16* Qh = Q   + (size_t)hq * SEQ * HD;

  // Q fragments: wave owns rows qb + wid*16 .. +15
  bf16x8 qf[4];
#pragma unroll
  for (int ks = 0; ks < 4; ks++)
    qf[ks] = *(const bf16x8*)(Qh + (size_t)(qb + wid*16 + l16) * HD + ks*32 + lhi*8);

  const f32x4 vz = {0.f, 0.f, 0.f, 0.f};
  f32x4 o[8];
  float mrow[4], lrow[4];
#pragma unroll
  for (int n = 0; n < 8; n++) o[n] = vz;
#pragma unroll
  for (int i = 0; i < 4; i++){ mrow[i] = -1e30f; lrow[i] = 0.f; }

  // staging source pointers (pre-swizzled so linear LDS + swizzled read = identity)
  int krl0 = wid*8 + (lane >> 4), krl1 = krl0 + 4;          // K rows (8/wave, 2 issues)
  int kgs  = lane & 15;
  const u16* ks0 = Kh + (size_t)krl0 * HD + ((kgs ^ (krl0 & 7)) << 3);
  const u16* ks1 = Kh + (size_t)krl1 * HD + ((kgs ^ (krl1 & 7)) << 3);
  int vrl0 = wid*16 + (lane >> 3), vrl1 = vrl0 + 8;         // V d-rows (16/wave, 2 issues)
  int vgs  = lane & 7;
  const u16* vs0 = Vh + (size_t)vrl0 * SEQ + ((vgs ^ (vrl0 & 7)) << 3);
  const u16* vs1 = Vh + (size_t)vrl1 * SEQ + ((vgs ^ (vrl1 & 7)) << 3);

  // prologue: stage tile 0 into buffer 0
  gload16(ks0, &Ksm[0][wid*8][0]);
  gload16(ks1, &Ksm[0][wid*8 + 4][0]);
  gload16(vs0, &Vsm[0][wid*16][0]);
  gload16(vs1, &Vsm[0][wid*16 + 8][0]);
  __syncthreads();

  int ntr = 2*J + 2;
  int wrow0 = qb + wid*16;
  for (int t = 0; t < ntr; t++){
    int cur = t & 1, nxt = cur ^ 1;
    int kt0 = t << 6;
    if (t < ntr - 1){  // async prefetch tile t+1 (overlaps whole trip; drained at barrier)
      size_t ko = (size_t)(t + 1) * 64 * HD;
      gload16(ks0 + ko, &Ksm[nxt][wid*8][0]);
      gload16(ks1 + ko, &Ksm[nxt][wid*8 + 4][0]);
      int vo = (t + 1) * 64;
      gload16(vs0 + vo, &Vsm[nxt][wid*16][0]);
      gload16(vs1 + vo, &Vsm[nxt][wid*16 + 8][0]);
    }
    if (kt0 <= wrow0 + 15){   // wave has unmasked rows in this tile
      // QK^T from swizzled Ksm
      f32x4 s[4];
#pragma unroll
      for (int n = 0; n < 4; n++) s[n] = vz;
      const u16* kbase = &Ksm[cur][0][0];
#pragma unroll
      for (int n = 0; n < 4; n++){
        int row = n*16 + l16, rxk = row & 7;
#pragma unroll
        for (int ks = 0; ks < 4; ks++){
          bf16x8 kf = *(const bf16x8*)(kbase + row*128 + (((ks*4 + lhi) ^ rxk) << 3));
          s[n] = mfma16(qf[ks], kf, s[n]);
        }
      }
      // causal mask (diagonal region only)
      if (kt0 + 63 > wrow0){
#pragma unroll
        for (int n = 0; n < 4; n++)
#pragma unroll
          for (int i = 0; i < 4; i++)
            if (kt0 + n*16 + l16 > wrow0 + lhi*4 + i) s[n][i] = -1e30f;
      }
      // online softmax (row q lives in 16 lanes sharing lhi*4+i)
#pragma unroll
      for (int i = 0; i < 4; i++){
        float tm = fmaxf(fmaxf(s[0][i], s[1][i]), fmaxf(s[2][i], s[3][i]));
        tm = fmaxf(tm, __shfl_xor(tm, 1));
        tm = fmaxf(tm, __shfl_xor(tm, 2));
        tm = fmaxf(tm, __shfl_xor(tm, 4));
        tm = fmaxf(tm, __shfl_xor(tm, 8));
        float nm = fmaxf(mrow[i], tm);
        float sc = __expf(mrow[i] - nm);
        mrow[i] = nm;
        float rsum = 0.f;
#pragma unroll
        for (int n = 0; n < 4; n++){
          float p = __expf(s[n][i] - nm);
          s[n][i] = p;
          rsum += p;
        }
        rsum += __shfl_xor(rsum, 1);
        rsum += __shfl_xor(rsum, 2);
        rsum += __shfl_xor(rsum, 4);
        rsum += __shfl_xor(rsum, 8);
        lrow[i] = lrow[i] * sc + rsum;
#pragma unroll
        for (int n = 0; n < 8; n++) o[n][i] *= sc;
      }
      // P (D-layout) -> per-wave LDS (no barrier: same-wave producer/consumer)
#pragma unroll
      for (int n = 0; n < 4; n++)
#pragma unroll
        for (int i = 0; i < 4; i++)
          Psm[wid][lhi*4 + i][n*16 + l16] = f2bf(s[n][i]);
      // PV from swizzled Vsm
      const u16* vbase = &Vsm[cur][0][0];
#pragma unroll
      for (int ksv = 0; ksv < 2; ksv++){
        bf16x8 pa = *(const bf16x8*)&Psm[wid][l16][ksv*32 + lhi*8];
#pragma unroll
        for (int n = 0; n < 8; n++){
          int row = n*16 + l16;
          bf16x8 vb = *(const bf16x8*)(vbase + row*64 + ((((ksv*4) + lhi) ^ (row & 7)) << 3));
          o[n] = mfma16(pa, vb, o[n]);
        }
      }
    }
    if (t < ntr - 1) __syncthreads();  // drains prefetch (vmcnt0) + swaps buffers
  }
  // epilogue: O /= l, write bf16 to AO[t][hq*128 + d]
  float inv[4];
#pragma unroll
  for (int i = 0; i < 4; i++) inv[i] = 1.f / lrow[i];
#pragma unroll
  for (int n = 0; n < 8; n++)
#pragma unroll
    for (int i = 0; i < 4; i++){
      int trow = wrow0 + lhi*4 + i;
      AO[(size_t)trow * HID + hq * HD + n*16 + l16] = f2bf(o[n][i] * inv[i]);
    }
}

// ---------------- launch ----------------
extern "C" void kernel_launch(void* const* d_in, const int* in_sizes, int n_in,
                              void* d_out, int out_size, void* d_ws, size_t ws_size,
                              hipStream_t stream){
  const float* hs   = (const float*)d_in[0];
  const float* cosp = (const float*)d_in[1];
  const float* sinp = (const float*)d_in[2];
  const float* wqkv = (const float*)d_in[3];
  const float* wo   = (const float*)d_in[4];
  const float* qw   = (const float*)d_in[5];
  const float* kw   = (const float*)d_in[6];
  float* out = (float*)d_out;
  char* ws = (char*)d_ws;
  // workspace layout (128 MB total); WOT reuses XB/WQKVT region after GEMM1
  u16* XB    = (u16*)(ws + 0);            // 16.8 MB  X bf16 [2048][4096]
  u16* WQKVT = (u16*)(ws + 16777216);     // 50.3 MB  WqkvT bf16 [6144][4096]
  u16* WOT   = (u16*)(ws + 0);            // 33.6 MB  WoT bf16 [4096][4096] (after GEMM1)
  u16* QKV   = (u16*)(ws + 67108864);     // 25.2 MB  qkv bf16 [2048][6144]
  u16* QR    = (u16*)(ws + 92274688);     // 16.8 MB  Q bf16 [32][2048][128]
  u16* KR    = (u16*)(ws + 109051904);    //  4.2 MB  K bf16 [8][2048][128]
  u16* VTB   = (u16*)(ws + 113246208);    //  4.2 MB  VT bf16 [8][128][2048]
  u16* AOB   = (u16*)(ws + 117440512);    // 16.8 MB  attn out bf16 [2048][4096]

  k_cvt<<<(SEQ * HID / 4 + 255) / 256, 256, 0, stream>>>(hs, XB, SEQ * HID / 4);
  k_transpose_cvt<<<dim3(QKVN / 32, HID / 32), dim3(32, 8), 0, stream>>>(wqkv, WQKVT, HID, QKVN);
  k_gemm<8, 1><<<dim3(QKVN / 256, SEQ / 256), 512, 0, stream>>>(XB, WQKVT, QKV, SEQ, QKVN, HID);
  k_transpose_cvt<<<dim3(HID / 32, HID / 32), dim3(32, 8), 0, stream>>>(wo, WOT, HID, HID);
  k_rmsrope<<<dim3(SEQ, 10), 256, 0, stream>>>(QKV, cosp, sinp, qw, kw, QR, KR);
  k_vt<<<dim3(SEQ / 32, HD / 32, NKVH), dim3(32, 8), 0, stream>>>(QKV, VTB);
  k_attn<<<512, 512, 0, stream>>>(QR, KR, VTB, AOB);
  k_gemm<4, 0><<<dim3(HID / 256, SEQ / 128), 512, 0, stream>>>(AOB, WOT, out, SEQ, HID, HID);
}

// Round 8
// 367.514 us; speedup vs baseline: 1.1528x; 1.1528x over previous
//
#include <hip/hip_runtime.h>
#include <stdint.h>

#define SEQ   2048
#define HID   4096
#define NQH   32
#define NKVH  8
#define HD    128
#define QKVN  6144   // (32 + 2*8) * 128

typedef uint16_t u16;
typedef __attribute__((ext_vector_type(8))) short bf16x8;
typedef __attribute__((ext_vector_type(4))) float f32x4;
typedef __attribute__((ext_vector_type(4))) unsigned int u32x4;

static __device__ __forceinline__ float bf2f(u16 h){
  union { float f; unsigned int u; } v; v.u = ((unsigned int)h) << 16; return v.f;
}
static __device__ __forceinline__ u16 f2bf(float f){
  unsigned int u = __float_as_uint(f);
  return (u16)((u + 0x7fffu + ((u >> 16) & 1u)) >> 16);  // RNE, finite inputs only
}
static __device__ __forceinline__ f32x4 mfma16(bf16x8 a, bf16x8 b, f32x4 c){
  return __builtin_amdgcn_mfma_f32_16x16x32_bf16(a, b, c, 0, 0, 0);
}
static __device__ __forceinline__ void gload16(const void* g, void* l){
  __builtin_amdgcn_global_load_lds((const __attribute__((address_space(1))) void*)g,
                                   (__attribute__((address_space(3))) void*)l, 16, 0, 0);
}

// ---------------- fp32 -> bf16 elementwise (n4 = n/4) ----------------
__global__ void k_cvt(const float* __restrict__ src, u16* __restrict__ dst, int n4){
  int i = blockIdx.x * blockDim.x + threadIdx.x;
  if (i >= n4) return;
  float4 v = ((const float4*)src)[i];
  uint2 o;
  o.x = (unsigned)f2bf(v.x) | ((unsigned)f2bf(v.y) << 16);
  o.y = (unsigned)f2bf(v.z) | ((unsigned)f2bf(v.w) << 16);
  ((uint2*)dst)[i] = o;
}

// ---------------- o += a (fp32, n4 = n/4) ----------------
__global__ void k_addf(const float* __restrict__ a, float* __restrict__ o, int n4){
  int i = blockIdx.x * blockDim.x + threadIdx.x;
  if (i >= n4) return;
  float4 x = ((const float4*)o)[i];
  float4 y = ((const float4*)a)[i];
  x.x += y.x; x.y += y.y; x.z += y.z; x.w += y.w;
  ((float4*)o)[i] = x;
}

// ---------------- src[K][N] fp32 -> dst[N][K] bf16 (transpose-convert) ----------------
__global__ void k_transpose_cvt(const float* __restrict__ src, u16* __restrict__ dst, int K, int N){
  __shared__ float t[32][33];
  int n0 = blockIdx.x * 32, k0 = blockIdx.y * 32;
  int tx = threadIdx.x, ty = threadIdx.y;
#pragma unroll
  for (int i = 0; i < 32; i += 8)
    t[ty + i][tx] = src[(size_t)(k0 + ty + i) * N + n0 + tx];
  __syncthreads();
#pragma unroll
  for (int i = 0; i < 32; i += 8)
    dst[(size_t)(n0 + ty + i) * K + k0 + tx] = f2bf(t[tx][ty + i]);
}

// ---------------- C[M][N] = A[M][K] @ Bt[N][K]^T, bf16 in, OUTBF? bf16 : fp32 out ----------------
// r5 structure (best measured): BM=BN=256, BK=64, 512 thr / 8 waves (2M x 4N),
// wave tile 128x64, 4 phases of 16-MFMA clusters with barrier pairs, LDS 128 KB
// double-buffer, tile t+1's 8 gloads issued in phases 0-1 (full-tile slack).
// SPLITK: blockIdx.z selects K-half; z=0 -> Cv0, z=1 -> Cv1 (merged by k_addf).
// Granule XOR swizzle g^=(row&7) both sides (measured: 0 bank conflicts).
template<int OUTBF, int SPLITK>
__global__ __launch_bounds__(512) void k_gemm(const u16* __restrict__ A, const u16* __restrict__ Bt,
                                              void* __restrict__ Cv0, void* __restrict__ Cv1,
                                              int M, int N, int K){
  __shared__ __align__(16) u16 Asm[2][256][64];   // 64 KB
  __shared__ __align__(16) u16 Bsm[2][256][64];   // 64 KB
  const int tid = threadIdx.x, lane = tid & 63, wid = tid >> 6;
  const int wm = wid >> 2, wn = wid & 3;          // 2 x 4 wave grid
  const int l16 = lane & 15, lhi = lane >> 4;
  const int rx = l16 & 7;                          // read-side swizzle key (= row&7)
  const size_t brow = (size_t)blockIdx.y * 256, bcol = (size_t)blockIdx.x * 256;
  const int kz = (SPLITK > 1) ? blockIdx.z : 0;
  const int kbeg = kz * (K / SPLITK);
  void* Cv = (kz == 0) ? Cv0 : Cv1;

  const f32x4 vz = {0.f, 0.f, 0.f, 0.f};
  f32x4 acc[8][4];
#pragma unroll
  for (int m = 0; m < 8; m++)
#pragma unroll
    for (int n = 0; n < 4; n++) acc[m][n] = vz;

  // staging: 4 gloads per matrix per wave per K-tile; gload j covers rows wid*8 + j*64 .. +7
  const int srow = lane >> 3;                      // row within 8-row group
  const int sg   = (lane & 7) ^ srow;              // pre-swizzled source granule
  const u16* Ags = A  + (brow + wid*8 + srow) * (size_t)K + sg*8 + kbeg;
  const u16* Bgs = Bt + (bcol + wid*8 + srow) * (size_t)K + sg*8 + kbeg;
  const int NT = (K / SPLITK) >> 6;

  // prologue: stage tile 0 -> buf 0
#pragma unroll
  for (int j = 0; j < 4; j++) gload16(Ags + (size_t)j*64*K, &Asm[0][wid*8 + j*64][0]);
#pragma unroll
  for (int j = 0; j < 4; j++) gload16(Bgs + (size_t)j*64*K, &Bsm[0][wid*8 + j*64][0]);
  asm volatile("s_waitcnt vmcnt(0)" ::: "memory");
  __builtin_amdgcn_sched_barrier(0);
  __builtin_amdgcn_s_barrier();

  for (int t = 0; t < NT; ++t){
    const int cur = t & 1, nxt = cur ^ 1;
    const size_t ko = (size_t)(t + 1) * 64;
    const bool st = (t + 1 < NT);
    bf16x8 a[8], b0, b1, b2, b3;
    // ---------- phase 0: A(kh0) x8 + B ni0,ni1(kh0); stage A0,A1,B0,B1 of t+1 ----------
#pragma unroll
    for (int mi = 0; mi < 8; ++mi)
      a[mi] = *(const bf16x8*)&Asm[cur][wm*128 + mi*16 + l16][(lhi ^ rx) << 3];
    b0 = *(const bf16x8*)&Bsm[cur][wn*64 +  0 + l16][(lhi ^ rx) << 3];
    b1 = *(const bf16x8*)&Bsm[cur][wn*64 + 16 + l16][(lhi ^ rx) << 3];
    if (st){
      gload16(Ags + ko,                  &Asm[nxt][wid*8      ][0]);
      gload16(Ags + (size_t)64*K + ko,   &Asm[nxt][wid*8 +  64][0]);
      gload16(Bgs + ko,                  &Bsm[nxt][wid*8      ][0]);
      gload16(Bgs + (size_t)64*K + ko,   &Bsm[nxt][wid*8 +  64][0]);
    }
    __builtin_amdgcn_s_barrier();
    asm volatile("s_waitcnt lgkmcnt(0)" ::: "memory");
    __builtin_amdgcn_sched_barrier(0);
    __builtin_amdgcn_s_setprio(1);
#pragma unroll
    for (int mi = 0; mi < 8; ++mi){
      acc[mi][0] = mfma16(a[mi], b0, acc[mi][0]);
      acc[mi][1] = mfma16(a[mi], b1, acc[mi][1]);
    }
    __builtin_amdgcn_s_setprio(0);
    __builtin_amdgcn_s_barrier();
    // ---------- phase 1: B ni2,ni3(kh0); stage A2,A3,B2,B3 of t+1 ----------
    b2 = *(const bf16x8*)&Bsm[cur][wn*64 + 32 + l16][(lhi ^ rx) << 3];
    b3 = *(const bf16x8*)&Bsm[cur][wn*64 + 48 + l16][(lhi ^ rx) << 3];
    if (st){
      gload16(Ags + (size_t)128*K + ko,  &Asm[nxt][wid*8 + 128][0]);
      gload16(Ags + (size_t)192*K + ko,  &Asm[nxt][wid*8 + 192][0]);
      gload16(Bgs + (size_t)128*K + ko,  &Bsm[nxt][wid*8 + 128][0]);
      gload16(Bgs + (size_t)192*K + ko,  &Bsm[nxt][wid*8 + 192][0]);
    }
    __builtin_amdgcn_s_barrier();
    asm volatile("s_waitcnt lgkmcnt(0)" ::: "memory");
    __builtin_amdgcn_sched_barrier(0);
    __builtin_amdgcn_s_setprio(1);
#pragma unroll
    for (int mi = 0; mi < 8; ++mi){
      acc[mi][2] = mfma16(a[mi], b2, acc[mi][2]);
      acc[mi][3] = mfma16(a[mi], b3, acc[mi][3]);
    }
    __builtin_amdgcn_s_setprio(0);
    __builtin_amdgcn_s_barrier();
    // ---------- phase 2: A(kh1) x8 + B ni0,ni1(kh1) ----------
#pragma unroll
    for (int mi = 0; mi < 8; ++mi)
      a[mi] = *(const bf16x8*)&Asm[cur][wm*128 + mi*16 + l16][((4 + lhi) ^ rx) << 3];
    b0 = *(const bf16x8*)&Bsm[cur][wn*64 +  0 + l16][((4 + lhi) ^ rx) << 3];
    b1 = *(const bf16x8*)&Bsm[cur][wn*64 + 16 + l16][((4 + lhi) ^ rx) << 3];
    __builtin_amdgcn_s_barrier();
    asm volatile("s_waitcnt lgkmcnt(0)" ::: "memory");
    __builtin_amdgcn_sched_barrier(0);
    __builtin_amdgcn_s_setprio(1);
#pragma unroll
    for (int mi = 0; mi < 8; ++mi){
      acc[mi][0] = mfma16(a[mi], b0, acc[mi][0]);
      acc[mi][1] = mfma16(a[mi], b1, acc[mi][1]);
    }
    __builtin_amdgcn_s_setprio(0);
    __builtin_amdgcn_s_barrier();
    // ---------- phase 3: B ni2,ni3(kh1); end-of-tile vmcnt drain (pre-satisfied) ----------
    b2 = *(const bf16x8*)&Bsm[cur][wn*64 + 32 + l16][((4 + lhi) ^ rx) << 3];
    b3 = *(const bf16x8*)&Bsm[cur][wn*64 + 48 + l16][((4 + lhi) ^ rx) << 3];
    __builtin_amdgcn_s_barrier();
    asm volatile("s_waitcnt lgkmcnt(0)" ::: "memory");
    __builtin_amdgcn_sched_barrier(0);
    __builtin_amdgcn_s_setprio(1);
#pragma unroll
    for (int mi = 0; mi < 8; ++mi){
      acc[mi][2] = mfma16(a[mi], b2, acc[mi][2]);
      acc[mi][3] = mfma16(a[mi], b3, acc[mi][3]);
    }
    __builtin_amdgcn_s_setprio(0);
    if (st){
      asm volatile("s_waitcnt vmcnt(0)" ::: "memory");  // tile t+1 landed (issued ~3 phases ago)
      __builtin_amdgcn_sched_barrier(0);
    }
    __builtin_amdgcn_s_barrier();
  }

  // epilogue: C/D layout col=l16, row=lhi*4+i
#pragma unroll
  for (int mi = 0; mi < 8; mi++)
#pragma unroll
    for (int ni = 0; ni < 4; ni++)
#pragma unroll
      for (int i = 0; i < 4; i++){
        size_t row = brow + wm*128 + mi*16 + lhi*4 + i;
        size_t col = bcol + wn*64 + ni*16 + l16;
        if (OUTBF) ((u16*)Cv)[row * (size_t)N + col] = f2bf(acc[mi][ni][i]);
        else       ((float*)Cv)[row * (size_t)N + col] = acc[mi][ni][i];
      }
}

// ---------------- RMSNorm + RoPE: qkv bf16 -> Q[h][t][d], K[h][t][d] (scale folded into Q) ----------------
__global__ __launch_bounds__(256) void k_rmsrope(const u16* __restrict__ qkv, const float* __restrict__ cosp,
                                                 const float* __restrict__ sinp, const float* __restrict__ qw,
                                                 const float* __restrict__ kw, u16* __restrict__ Qr,
                                                 u16* __restrict__ Kr){
  int t = blockIdx.x;
  int lane = threadIdx.x & 63, w = threadIdx.x >> 6;
  int hh = blockIdx.y * 4 + w;          // 0..39: 32 q heads + 8 k heads
  bool isq = hh < NQH;
  int hl = isq ? hh : hh - NQH;
  const u16* src = qkv + (size_t)t * QKVN + (isq ? hl * HD : NQH * HD + hl * HD);
  unsigned u = *(const unsigned*)(src + 2 * lane);       // d = 2*lane, 2*lane+1
  float x0 = bf2f((u16)(u & 0xffffu)), x1 = bf2f((u16)(u >> 16));
  float ss = x0 * x0 + x1 * x1;
#pragma unroll
  for (int m = 1; m < 64; m <<= 1) ss += __shfl_xor(ss, m);
  float rs = rsqrtf(ss * (1.f / HD) + 1e-6f);
  const float* wp = isq ? qw : kw;
  float w0 = wp[2 * lane], w1 = wp[2 * lane + 1];
  float xn0 = x0 * rs * w0, xn1 = x1 * rs * w1;
  float p0 = __shfl_xor(xn0, 32), p1 = __shfl_xor(xn1, 32);  // rotate-half partner
  int j0 = (2 * lane) & 63;
  float c0 = cosp[t * 64 + j0], c1 = cosp[t * 64 + j0 + 1];
  float s0 = sinp[t * 64 + j0], s1 = sinp[t * 64 + j0 + 1];
  float o0, o1;
  if (lane < 32){ o0 = xn0 * c0 - p0 * s0; o1 = xn1 * c1 - p1 * s1; }
  else          { o0 = xn0 * c0 + p0 * s0; o1 = xn1 * c1 + p1 * s1; }
  if (isq){ o0 *= 0.08838834764831845f; o1 *= 0.08838834764831845f; }  // D^-0.5
  u16* dst = isq ? (Qr + ((size_t)hl * SEQ + t) * HD) : (Kr + ((size_t)hl * SEQ + t) * HD);
  *(unsigned*)(dst + 2 * lane) = (unsigned)f2bf(o0) | ((unsigned)f2bf(o1) << 16);
}

// ---------------- V slice of qkv -> VT[h][d][t] bf16 ----------------
__global__ void k_vt(const u16* __restrict__ qkv, u16* __restrict__ VT){
  __shared__ u16 t[32][33];
  int t0 = blockIdx.x * 32, d0 = blockIdx.y * 32, hv = blockIdx.z;
  int tx = threadIdx.x, ty = threadIdx.y;
#pragma unroll
  for (int i = 0; i < 32; i += 8)
    t[ty + i][tx] = qkv[(size_t)(t0 + ty + i) * QKVN + (NQH + NKVH) * HD + hv * HD + d0 + tx];
  __syncthreads();
#pragma unroll
  for (int i = 0; i < 32; i += 8)
    VT[((size_t)hv * HD + d0 + ty + i) * SEQ + t0 + tx] = t[tx][ty + i];
}

// ---------------- causal GQA flash attention ----------------
// 512 blocks (8 waves, 512 thr): one 128-row q-tile per block, longest-first.
// bid -> kvg=bid&7 (XCD L2 locality), J=15-(rr>>2) desc.
// K[64][128] and VT[128][64] double-buffered in LDS via global_load_lds with
// G21 XOR-swizzle (linear dest + inverse-swizzled source + swizzled ds_read).
// One barrier per KV tile; tile t+1 prefetch issued at trip t start.
__global__ __launch_bounds__(512, 2) void k_attn(const u16* __restrict__ Q, const u16* __restrict__ Kg,
                                                 const u16* __restrict__ VTg, u16* __restrict__ AO){
  __shared__ __align__(16) u16 Ksm[2][64][128];   // [buf][kv][d], 16B-granule swizzled
  __shared__ __align__(16) u16 Vsm[2][128][64];   // [buf][d][kv], swizzled
  __shared__ __align__(16) u16 Psm[8][16][72];    // per-wave P [q][kv]
  int tid = threadIdx.x, lane = tid & 63, wid = tid >> 6;
  int l16 = lane & 15, lhi = lane >> 4;
  int bid = blockIdx.x;
  int kvg = bid & 7, rr = bid >> 3;               // 64 blocks per kv-group
  int J = 15 - (rr >> 2);                         // longest-first
  int hq = kvg * 4 + (rr & 3);
  int qb = J * 128;
  const u16* Kh = Kg  + (size_t)kvg * SEQ * HD;
  const u16* Vh = VTg + (size_t)kvg * HD * SEQ;
  const u16* Qh = Q   + (size_t)hq * SEQ * HD;

  // Q fragments: wave owns rows qb + wid*16 .. +15
  bf16x8 qf[4];
#pragma unroll
  for (int ks = 0; ks < 4; ks++)
    qf[ks] = *(const bf16x8*)(Qh + (size_t)(qb + wid*16 + l16) * HD + ks*32 + lhi*8);

  const f32x4 vz = {0.f, 0.f, 0.f, 0.f};
  f32x4 o[8];
  float mrow[4], lrow[4];
#pragma unroll
  for (int n = 0; n < 8; n++) o[n] = vz;
#pragma unroll
  for (int i = 0; i < 4; i++){ mrow[i] = -1e30f; lrow[i] = 0.f; }

  // staging source pointers (pre-swizzled so linear LDS + swizzled read = identity)
  int krl0 = wid*8 + (lane >> 4), krl1 = krl0 + 4;          // K rows (8/wave, 2 issues)
  int kgs  = lane & 15;
  const u16* ks0 = Kh + (size_t)krl0 * HD + ((kgs ^ (krl0 & 7)) << 3);
  const u16* ks1 = Kh + (size_t)krl1 * HD + ((kgs ^ (krl1 & 7)) << 3);
  int vrl0 = wid*16 + (lane >> 3), vrl1 = vrl0 + 8;         // V d-rows (16/wave, 2 issues)
  int vgs  = lane & 7;
  const u16* vs0 = Vh + (size_t)vrl0 * SEQ + ((vgs ^ (vrl0 & 7)) << 3);
  const u16* vs1 = Vh + (size_t)vrl1 * SEQ + ((vgs ^ (vrl1 & 7)) << 3);

  // prologue: stage tile 0 into buffer 0
  gload16(ks0, &Ksm[0][wid*8][0]);
  gload16(ks1, &Ksm[0][wid*8 + 4][0]);
  gload16(vs0, &Vsm[0][wid*16][0]);
  gload16(vs1, &Vsm[0][wid*16 + 8][0]);
  __syncthreads();

  int ntr = 2*J + 2;
  int wrow0 = qb + wid*16;
  for (int t = 0; t < ntr; t++){
    int cur = t & 1, nxt = cur ^ 1;
    int kt0 = t << 6;
    if (t < ntr - 1){  // async prefetch tile t+1 (overlaps whole trip; drained at barrier)
      size_t ko = (size_t)(t + 1) * 64 * HD;
      gload16(ks0 + ko, &Ksm[nxt][wid*8][0]);
      gload16(ks1 + ko, &Ksm[nxt][wid*8 + 4][0]);
      int vo = (t + 1) * 64;
      gload16(vs0 + vo, &Vsm[nxt][wid*16][0]);
      gload16(vs1 + vo, &Vsm[nxt][wid*16 + 8][0]);
    }
    if (kt0 <= wrow0 + 15){   // wave has unmasked rows in this tile
      // QK^T from swizzled Ksm
      f32x4 s[4];
#pragma unroll
      for (int n = 0; n < 4; n++) s[n] = vz;
      const u16* kbase = &Ksm[cur][0][0];
#pragma unroll
      for (int n = 0; n < 4; n++){
        int row = n*16 + l16, rxk = row & 7;
#pragma unroll
        for (int ks = 0; ks < 4; ks++){
          bf16x8 kf = *(const bf16x8*)(kbase + row*128 + (((ks*4 + lhi) ^ rxk) << 3));
          s[n] = mfma16(qf[ks], kf, s[n]);
        }
      }
      // causal mask (diagonal region only)
      if (kt0 + 63 > wrow0){
#pragma unroll
        for (int n = 0; n < 4; n++)
#pragma unroll
          for (int i = 0; i < 4; i++)
            if (kt0 + n*16 + l16 > wrow0 + lhi*4 + i) s[n][i] = -1e30f;
      }
      // online softmax (row q lives in 16 lanes sharing lhi*4+i)
#pragma unroll
      for (int i = 0; i < 4; i++){
        float tm = fmaxf(fmaxf(s[0][i], s[1][i]), fmaxf(s[2][i], s[3][i]));
        tm = fmaxf(tm, __shfl_xor(tm, 1));
        tm = fmaxf(tm, __shfl_xor(tm, 2));
        tm = fmaxf(tm, __shfl_xor(tm, 4));
        tm = fmaxf(tm, __shfl_xor(tm, 8));
        float nm = fmaxf(mrow[i], tm);
        float sc = __expf(mrow[i] - nm);
        mrow[i] = nm;
        float rsum = 0.f;
#pragma unroll
        for (int n = 0; n < 4; n++){
          float p = __expf(s[n][i] - nm);
          s[n][i] = p;
          rsum += p;
        }
        rsum += __shfl_xor(rsum, 1);
        rsum += __shfl_xor(rsum, 2);
        rsum += __shfl_xor(rsum, 4);
        rsum += __shfl_xor(rsum, 8);
        lrow[i] = lrow[i] * sc + rsum;
#pragma unroll
        for (int n = 0; n < 8; n++) o[n][i] *= sc;
      }
      // P (D-layout) -> per-wave LDS (no barrier: same-wave producer/consumer)
#pragma unroll
      for (int n = 0; n < 4; n++)
#pragma unroll
        for (int i = 0; i < 4; i++)
          Psm[wid][lhi*4 + i][n*16 + l16] = f2bf(s[n][i]);
      // PV from swizzled Vsm
      const u16* vbase = &Vsm[cur][0][0];
#pragma unroll
      for (int ksv = 0; ksv < 2; ksv++){
        bf16x8 pa = *(const bf16x8*)&Psm[wid][l16][ksv*32 + lhi*8];
#pragma unroll
        for (int n = 0; n < 8; n++){
          int row = n*16 + l16;
          bf16x8 vb = *(const bf16x8*)(vbase + row*64 + ((((ksv*4) + lhi) ^ (row & 7)) << 3));
          o[n] = mfma16(pa, vb, o[n]);
        }
      }
    }
    if (t < ntr - 1) __syncthreads();  // drains prefetch (vmcnt0) + swaps buffers
  }
  // epilogue: O /= l, write bf16 to AO[t][hq*128 + d]
  float inv[4];
#pragma unroll
  for (int i = 0; i < 4; i++) inv[i] = 1.f / lrow[i];
#pragma unroll
  for (int n = 0; n < 8; n++)
#pragma unroll
    for (int i = 0; i < 4; i++){
      int trow = wrow0 + lhi*4 + i;
      AO[(size_t)trow * HID + hq * HD + n*16 + l16] = f2bf(o[n][i] * inv[i]);
    }
}

// ---------------- launch ----------------
extern "C" void kernel_launch(void* const* d_in, const int* in_sizes, int n_in,
                              void* d_out, int out_size, void* d_ws, size_t ws_size,
                              hipStream_t stream){
  const float* hs   = (const float*)d_in[0];
  const float* cosp = (const float*)d_in[1];
  const float* sinp = (const float*)d_in[2];
  const float* wqkv = (const float*)d_in[3];
  const float* wo   = (const float*)d_in[4];
  const float* qw   = (const float*)d_in[5];
  const float* kw   = (const float*)d_in[6];
  float* out = (float*)d_out;
  char* ws = (char*)d_ws;
  // workspace layout (128 MB total); WOT reuses XB region after GEMM1; SCR (split-K
  // fp32 partial, 33.55 MB) reuses [33.5M, 67.1M) = rest of WQKVT region, dead after GEMM1.
  u16* XB    = (u16*)(ws + 0);            // 16.8 MB  X bf16 [2048][4096]
  u16* WQKVT = (u16*)(ws + 16777216);     // 50.3 MB  WqkvT bf16 [6144][4096]
  u16* WOT   = (u16*)(ws + 0);            // 33.6 MB  WoT bf16 [4096][4096] (after GEMM1)
  float* SCR = (float*)(ws + 33554432);   // 33.6 MB  fp32 partial [2048][4096]
  u16* QKV   = (u16*)(ws + 67108864);     // 25.2 MB  qkv bf16 [2048][6144]
  u16* QR    = (u16*)(ws + 92274688);     // 16.8 MB  Q bf16 [32][2048][128]
  u16* KR    = (u16*)(ws + 109051904);    //  4.2 MB  K bf16 [8][2048][128]
  u16* VTB   = (u16*)(ws + 113246208);    //  4.2 MB  VT bf16 [8][128][2048]
  u16* AOB   = (u16*)(ws + 117440512);    // 16.8 MB  attn out bf16 [2048][4096]

  k_cvt<<<(SEQ * HID / 4 + 255) / 256, 256, 0, stream>>>(hs, XB, SEQ * HID / 4);
  k_transpose_cvt<<<dim3(QKVN / 32, HID / 32), dim3(32, 8), 0, stream>>>(wqkv, WQKVT, HID, QKVN);
  k_gemm<1, 1><<<dim3(QKVN / 256, SEQ / 256), 512, 0, stream>>>(XB, WQKVT, QKV, nullptr, SEQ, QKVN, HID);
  k_transpose_cvt<<<dim3(HID / 32, HID / 32), dim3(32, 8), 0, stream>>>(wo, WOT, HID, HID);
  k_rmsrope<<<dim3(SEQ, 10), 256, 0, stream>>>(QKV, cosp, sinp, qw, kw, QR, KR);
  k_vt<<<dim3(SEQ / 32, HD / 32, NKVH), dim3(32, 8), 0, stream>>>(QKV, VTB);
  k_attn<<<512, 512, 0, stream>>>(QR, KR, VTB, AOB);
  k_gemm<0, 2><<<dim3(HID / 256, SEQ / 256, 2), 512, 0, stream>>>(AOB, WOT, out, SCR, SEQ, HID, HID);
  k_addf<<<SEQ * HID / 4 / 256, 256, 0, stream>>>(SCR, out, SEQ * HID / 4);
}